// Round 5
// baseline (1314.417 us; speedup 1.0000x reference)
//
#include <hip/hip_runtime.h>

// ---------------------------------------------------------------------------
// GCN stack: 9 layers of  h = relu( Â (h W) + b ),  Â = D^-1/2 (A+I) D^-1/2
//   * Â(HW) == (ÂH)W  -> aggregate at width min(din,dout) per layer
//   * Â identical across layers -> CSR (self-loops folded) built once
// R5: XCD-sliced chunk-major aggregation. Activations stored [chunk][node][32f]
//     (3.2 MB slices fit one XCD's 4 MB L2); blockIdx%8 XCD striping pins each
//     chunk to one XCD -> gather served at L2 instead of L3 (FETCH 188->~55MB).
//     Edges compressed to 4 B (u16 src | bf16 weight). GEMM writes chunk-major.
// ---------------------------------------------------------------------------

#define TPB 256

using bf16x8 = __attribute__((ext_vector_type(8))) __bf16;
using f32x4  = __attribute__((ext_vector_type(4))) float;

__device__ __forceinline__ unsigned bf16rne(float x) {
    unsigned u = __float_as_uint(x);
    return (u + 0x7fffu + ((u >> 16) & 1u)) >> 16;
}

// async global->LDS, 16B per lane. l is the WAVE-UNIFORM base; HW adds lane*16.
__device__ __forceinline__ void stage16(const unsigned short* g, unsigned short* l) {
#if __has_builtin(__builtin_amdgcn_global_load_lds)
    __builtin_amdgcn_global_load_lds((const __attribute__((address_space(1))) void*)g,
                                     (__attribute__((address_space(3))) void*)l, 16, 0, 0);
#else
    *(uint4*)((char*)l + (threadIdx.x & 63) * 16) = *(const uint4*)g;
#endif
}

// ---------------- graph prep kernels ----------------

__global__ void zero_int_kernel(int* p, int n) {
    int i = blockIdx.x * blockDim.x + threadIdx.x;
    if (i < n) p[i] = 0;
}

__global__ void count_kernel(const int* __restrict__ dst, int* __restrict__ cnt, int E) {
    int e = blockIdx.x * blockDim.x + threadIdx.x;
    if (e < E) atomicAdd(&cnt[dst[e]], 1);
}

__global__ void dinv_kernel(const int* __restrict__ cnt, float* __restrict__ dinv, int n) {
    int i = blockIdx.x * blockDim.x + threadIdx.x;
    if (i < n) dinv[i] = rsqrtf((float)(cnt[i] + 1));
}

__global__ void scan1_kernel(const int* __restrict__ cnt, int* __restrict__ rowp,
                             int* __restrict__ bsums, int n) {
    __shared__ int sh[TPB];
    int t = threadIdx.x;
    int i = blockIdx.x * TPB + t;
    int v = (i < n) ? (cnt[i] + 1) : 0;       // +1 self loop in CSR
    sh[t] = v;
    __syncthreads();
    for (int off = 1; off < TPB; off <<= 1) {
        int x = (t >= off) ? sh[t - off] : 0;
        __syncthreads();
        sh[t] += x;
        __syncthreads();
    }
    if (i < n) rowp[i] = sh[t] - v;
    if (t == TPB - 1) bsums[blockIdx.x] = sh[t];
}

__global__ void scan2_kernel(int* __restrict__ bsums, int nb) {
    __shared__ int sh[TPB];
    int t = threadIdx.x;
    int v = (t < nb) ? bsums[t] : 0;
    sh[t] = v;
    __syncthreads();
    for (int off = 1; off < TPB; off <<= 1) {
        int x = (t >= off) ? sh[t - off] : 0;
        __syncthreads();
        sh[t] += x;
        __syncthreads();
    }
    if (t < nb) bsums[t] = sh[t] - v;
}

__global__ void scan3_kernel(int* __restrict__ rowp, const int* __restrict__ bsums, int n) {
    int i = blockIdx.x * TPB + threadIdx.x;
    if (i < n) rowp[i] += bsums[blockIdx.x];
}

// edge = u16 src | bf16(weight) << 16   (N=50000 < 65536)
__global__ void fill_kernel(const int* __restrict__ src, const int* __restrict__ dst,
                            const float* __restrict__ dinv,
                            const int* __restrict__ rowp, int* __restrict__ fill,
                            unsigned* __restrict__ edges, int E) {
    int e = blockIdx.x * blockDim.x + threadIdx.x;
    if (e >= E) return;
    int s = src[e], d = dst[e];
    int pos = rowp[d] + atomicAdd(&fill[d], 1);
    edges[pos] = (unsigned)s | (bf16rne(dinv[s] * dinv[d]) << 16);
}

__global__ void self_kernel(const int* __restrict__ cnt, const int* __restrict__ rowp,
                            const float* __restrict__ dinv, unsigned* __restrict__ edges,
                            int n) {
    int i = blockIdx.x * blockDim.x + threadIdx.x;
    if (i >= n) return;
    float dv = dinv[i];
    edges[rowp[i] + cnt[i]] = (unsigned)i | (bf16rne(dv * dv) << 16);
}

// ---------------- weight / input prep ----------------

// Wt[n*K + k] = bf16(W[k*N + n])
__global__ void wt_kernel(const float* __restrict__ W, unsigned short* __restrict__ Wt,
                          int K, int N) {
    int id = blockIdx.x * blockDim.x + threadIdx.x;
    if (id >= K * N) return;
    int k = id / N, n = id % N;
    Wt[n * K + k] = (unsigned short)bf16rne(W[id]);
}

__global__ void cvt_bf16_kernel(const float* __restrict__ in, unsigned short* __restrict__ out,
                                int n4) {
    int i = blockIdx.x * blockDim.x + threadIdx.x;
    if (i >= n4) return;
    float4 v = ((const float4*)in)[i];
    uint2 o;
    o.x = bf16rne(v.x) | (bf16rne(v.y) << 16);
    o.y = bf16rne(v.z) | (bf16rne(v.w) << 16);
    ((uint2*)out)[i] = o;
}

// ---------------- MFMA GEMM ----------------

// C[M,Nc] = A[M,K] @ W[K,Nc] (+bias,relu). A bf16 row-major, Wt bf16 [Nc][K].
// 128x128 block tile, 4 waves, each 4x4 tiles of 16x16x32 MFMA. K%32==0.
// Output bf16: row-major or chunk-major ([gc/32][gr][gc%32]).
__global__ __launch_bounds__(256) void gemm_mfma_kernel(
    const unsigned short* __restrict__ A, const unsigned short* __restrict__ Wt,
    const float* __restrict__ bias, unsigned short* __restrict__ C,
    int M, int K, int Nc, int doBias, int doRelu, int outChunked) {
    __shared__ unsigned short Ab[128 * 32];
    __shared__ unsigned short Bb[128 * 32];
    int tid = threadIdx.x;
    int l = tid & 63, w = tid >> 6;
    int row0 = blockIdx.y * 128, col0 = blockIdx.x * 128;

    f32x4 acc[4][4];
#pragma unroll
    for (int i = 0; i < 4; i++)
#pragma unroll
        for (int j = 0; j < 4; j++) acc[i][j] = (f32x4){0.f, 0.f, 0.f, 0.f};

    const unsigned short* gA[2];
    const unsigned short* gB[2];
    unsigned short* lA[2];
    unsigned short* lB[2];
#pragma unroll
    for (int h = 0; h < 2; h++) {
        int slot = tid + h * 256;
        int r = slot >> 2, q = slot & 3;
        int ar = row0 + r; if (ar > M - 1) ar = M - 1;
        int bn = col0 + r; if (bn > Nc - 1) bn = Nc - 1;
        gA[h] = A + (size_t)ar * K + q * 8;
        gB[h] = Wt + (size_t)bn * K + q * 8;
        lA[h] = Ab + (size_t)(w * 64 + h * 256) * 8;
        lB[h] = Bb + (size_t)(w * 64 + h * 256) * 8;
    }

    int q4 = l >> 4, m16 = l & 15;
    const unsigned short* ap[4];
    const unsigned short* bp[4];
#pragma unroll
    for (int i = 0; i < 4; i++) {
        int rA = (w & 1) * 64 + i * 16 + m16;
        int rB = (w >> 1) * 64 + i * 16 + m16;
        ap[i] = Ab + rA * 32 + q4 * 8;
        bp[i] = Bb + rB * 32 + q4 * 8;
    }

    for (int k0 = 0; k0 < K; k0 += 32) {
        __syncthreads();
#pragma unroll
        for (int h = 0; h < 2; h++) {
            stage16(gA[h] + k0, lA[h]);
            stage16(gB[h] + k0, lB[h]);
        }
        __syncthreads();
        bf16x8 af[4], bfr[4];
#pragma unroll
        for (int i = 0; i < 4; i++) af[i] = *(const bf16x8*)ap[i];
#pragma unroll
        for (int j = 0; j < 4; j++) bfr[j] = *(const bf16x8*)bp[j];
#pragma unroll
        for (int i = 0; i < 4; i++)
#pragma unroll
            for (int j = 0; j < 4; j++)
                acc[i][j] = __builtin_amdgcn_mfma_f32_16x16x32_bf16(af[i], bfr[j],
                                                                    acc[i][j], 0, 0, 0);
    }

    // C/D layout: col=lane&15, row=quad*4+reg
#pragma unroll
    for (int j = 0; j < 4; j++) {
        int gc = col0 + (w >> 1) * 64 + j * 16 + m16;
        if (gc >= Nc) continue;
        float bv = doBias ? bias[gc] : 0.f;
        size_t cbase = outChunked ? ((size_t)(gc >> 5) * ((size_t)M * 32) + (gc & 31))
                                  : (size_t)gc;
#pragma unroll
        for (int i = 0; i < 4; i++) {
            int gr0 = row0 + (w & 1) * 64 + i * 16 + q4 * 4;
            f32x4 v = acc[i][j];
#pragma unroll
            for (int reg = 0; reg < 4; reg++) {
                int gr = gr0 + reg;
                if (gr >= M) continue;
                float x = v[reg] + bv;
                if (doRelu) x = fmaxf(x, 0.f);
                size_t off = outChunked ? (cbase + (size_t)gr * 32)
                                        : (cbase + (size_t)gr * Nc);
                C[off] = (unsigned short)bf16rne(x);
            }
        }
    }
}

// out[m] = dot(A[m,0:128], w[0:128])  A bf16 row-major, one wave per row
__global__ void gemv128_bf16_kernel(const unsigned short* __restrict__ A,
                                    const float* __restrict__ w,
                                    float* __restrict__ out, int M) {
    int wid = (blockIdx.x * blockDim.x + threadIdx.x) >> 6;
    int lane = threadIdx.x & 63;
    if (wid >= M) return;
    const unsigned short* a = A + (size_t)wid * 128;
    float a0 = __uint_as_float((unsigned)a[lane] << 16);
    float a1 = __uint_as_float((unsigned)a[lane + 64] << 16);
    float s = a0 * w[lane] + a1 * w[lane + 64];
#pragma unroll
    for (int off = 32; off > 0; off >>= 1) s += __shfl_down(s, off);
    if (lane == 0) out[wid] = s;
}

// ---------------- chunked aggregation ----------------

// Input: bf16 chunk-major [chunk][node][32f] (64 B rows -> 3.2 MB slice / chunk).
// One wave per (node, chunk): 8 edge-groups x 8 lanes (uint2 = 4 feats/lane).
// blockIdx%8 = XCD; unit = xcd*U + blockIdx/8 sweeps (chunk, nodeGroup) so each
// XCD touches one chunk slice (or a contiguous span) -> L2-resident gather.
__global__ __launch_bounds__(256) void agg_chunk_kernel(
    const uint2* __restrict__ in, const int* __restrict__ rowp,
    const int* __restrict__ cnt, const unsigned* __restrict__ edges,
    const float* __restrict__ bias, uint2* __restrict__ out,
    int nchunks, int NG, int unitsPerXcd, int n_nodes, int rowVec2,
    int doBias, int doRelu, int outChunked) {
    int xcd = blockIdx.x & 7;
    int slot = blockIdx.x >> 3;
    int unit = xcd * unitsPerXcd + slot;
    if (unit >= nchunks * NG) return;
    int chunk = unit / NG;
    int ng = unit - chunk * NG;
    int node = ng * 4 + (threadIdx.x >> 6);
    if (node >= n_nodes) return;
    int lane = threadIdx.x & 63;
    int g = lane >> 3, fl = lane & 7;

    const uint2* slice = in + (size_t)chunk * n_nodes * 8;
    int s0 = rowp[node];
    int c = cnt[node] + 1;

    float ax = 0.f, ay = 0.f, az = 0.f, aw = 0.f;
    for (int j = g; j < c; j += 8) {
        unsigned e = edges[s0 + j];                       // broadcast within group
        float wgt = __uint_as_float(e & 0xffff0000u);     // bf16 weight, high bits
        int srcn = (int)(e & 0xffffu);
        uint2 p = slice[srcn * 8 + fl];
        ax += wgt * __uint_as_float(p.x << 16);
        ay += wgt * __uint_as_float(p.x & 0xffff0000u);
        az += wgt * __uint_as_float(p.y << 16);
        aw += wgt * __uint_as_float(p.y & 0xffff0000u);
    }
#pragma unroll
    for (int off = 32; off >= 8; off >>= 1) {
        ax += __shfl_down(ax, off);
        ay += __shfl_down(ay, off);
        az += __shfl_down(az, off);
        aw += __shfl_down(aw, off);
    }
    if (lane < 8) {
        if (doBias) {
            float4 bb = ((const float4*)bias)[chunk * 8 + fl];
            ax += bb.x; ay += bb.y; az += bb.z; aw += bb.w;
        }
        if (doRelu) {
            ax = fmaxf(ax, 0.f); ay = fmaxf(ay, 0.f);
            az = fmaxf(az, 0.f); aw = fmaxf(aw, 0.f);
        }
        uint2 o;
        o.x = bf16rne(ax) | (bf16rne(ay) << 16);
        o.y = bf16rne(az) | (bf16rne(aw) << 16);
        size_t oi = outChunked ? ((size_t)chunk * n_nodes * 8 + (size_t)node * 8 + fl)
                               : ((size_t)node * rowVec2 + chunk * 8 + fl);
        out[oi] = o;
    }
}

// width-1 aggregation, fp32: one thread per node
__global__ void agg1_kernel(const float* __restrict__ in, const int* __restrict__ rowp,
                            const int* __restrict__ cnt, const unsigned* __restrict__ edges,
                            const float* __restrict__ bias, float* __restrict__ out,
                            int n_nodes, int doRelu) {
    int n = blockIdx.x * blockDim.x + threadIdx.x;
    if (n >= n_nodes) return;
    float acc = 0.f;
    int s0 = rowp[n];
    int c = cnt[n] + 1;
    for (int j = 0; j < c; j++) {
        unsigned e = edges[s0 + j];
        acc += __uint_as_float(e & 0xffff0000u) * in[e & 0xffffu];
    }
    acc += bias[0];
    if (doRelu) acc = fmaxf(acc, 0.f);
    out[n] = acc;
}

// ---------------- host launcher ----------------

extern "C" void kernel_launch(void* const* d_in, const int* in_sizes, int n_in,
                              void* d_out, int out_size, void* d_ws, size_t ws_size,
                              hipStream_t stream) {
    const float* x = (const float*)d_in[0];
    const int* ei = (const int*)d_in[1];
    const int Nn = in_sizes[0] / 128;      // 50000
    const int E = in_sizes[1] / 2;         // 800000
    const int* src = ei;
    const int* dst = ei + E;

    char* ws = (char*)d_ws;
    size_t off = 0;
    auto alloc = [&](size_t bytes) -> char* {
        char* p = ws + off;
        off = (off + bytes + 255) & ~(size_t)255;
        return p;
    };
    int* cnt = (int*)alloc((size_t)Nn * 4);
    int* fill = (int*)alloc((size_t)Nn * 4);
    int* rowp = (int*)alloc((size_t)Nn * 4);
    int* bsums = (int*)alloc(1024);
    float* dinv = (float*)alloc((size_t)Nn * 4);
    unsigned* edges = (unsigned*)alloc((size_t)(E + Nn) * 4);
    unsigned short* T = (unsigned short*)alloc((size_t)Nn * 256 * 2);
    unsigned short* H = (unsigned short*)alloc((size_t)Nn * 256 * 2);
    unsigned short* Bx = (unsigned short*)alloc((size_t)Nn * 128 * 2);
    float* F = (float*)alloc((size_t)Nn * 4);
    unsigned short* Wts = (unsigned short*)alloc((size_t)400000 * 2);
    (void)ws_size;

    const int dims[9][2] = {{128,128},{128,192},{192,256},{256,256},{256,256},
                            {256,256},{256,192},{192,128},{128,1}};
    unsigned short* Wt[8];
    {
        size_t o = 0;
        for (int i = 0; i < 8; i++) { Wt[i] = Wts + o; o += (size_t)dims[i][0] * dims[i][1]; }
    }

    int nbN = (Nn + TPB - 1) / TPB;
    int nbE = (E + TPB - 1) / TPB;

    // ---- graph prep ----
    zero_int_kernel<<<nbN, TPB, 0, stream>>>(cnt, Nn);
    zero_int_kernel<<<nbN, TPB, 0, stream>>>(fill, Nn);
    count_kernel<<<nbE, TPB, 0, stream>>>(dst, cnt, E);
    dinv_kernel<<<nbN, TPB, 0, stream>>>(cnt, dinv, Nn);
    scan1_kernel<<<nbN, TPB, 0, stream>>>(cnt, rowp, bsums, Nn);
    scan2_kernel<<<1, TPB, 0, stream>>>(bsums, nbN);
    scan3_kernel<<<nbN, TPB, 0, stream>>>(rowp, bsums, Nn);
    fill_kernel<<<nbE, TPB, 0, stream>>>(src, dst, dinv, rowp, fill, edges, E);
    self_kernel<<<nbN, TPB, 0, stream>>>(cnt, rowp, dinv, edges, Nn);

    // ---- weight transpose + input convert ----
    for (int i = 0; i < 8; i++) {
        int K = dims[i][0], N = dims[i][1];
        wt_kernel<<<(K * N + TPB - 1) / TPB, TPB, 0, stream>>>(
            (const float*)d_in[2 + 2 * i], Wt[i], K, N);
    }
    cvt_bf16_kernel<<<(Nn * 32 + TPB - 1) / TPB, TPB, 0, stream>>>(x, Bx, Nn * 32);

    auto gemm = [&](const unsigned short* A, int i, unsigned short* C, int K, int Nc,
                    int doBias, int doRelu, int outChunked) {
        const float* b = (const float*)d_in[3 + 2 * i];
        dim3 grid((Nc + 127) / 128, (Nn + 127) / 128);
        gemm_mfma_kernel<<<grid, 256, 0, stream>>>(A, Wt[i], b, C, Nn, K, Nc,
                                                   doBias, doRelu, outChunked);
    };
    auto agg = [&](const unsigned short* inb, unsigned short* outb, int w, int i,
                   int doBias, int doRelu, int outChunked) {
        int nch = w / 32;
        int NG = (Nn + 3) / 4;
        int units = nch * NG;
        int U = (units + 7) / 8;
        const float* b = (const float*)d_in[3 + 2 * i];
        agg_chunk_kernel<<<U * 8, 256, 0, stream>>>((const uint2*)inb, rowp, cnt, edges,
                                                    b, (uint2*)outb, nch, NG, U, Nn,
                                                    w / 4, doBias, doRelu, outChunked);
    };

    // layout chain: GEMM in=row, out=chunked (except G2: row); agg in=chunked,
    // out=row (except A0: chunked, feeds A1)
    gemm(Bx, 0, T, 128, 128, 0, 0, 1);      // G0: t = x@W0          -> T chunked
    agg(T, H, 128, 0, 1, 1, 1);             // A0: h1 = At+b0 relu   -> H chunked
    agg(H, T, 128, 1, 0, 0, 0);             // A1: u = A h1          -> T row
    gemm(T, 1, H, 128, 192, 1, 1, 1);       // G1: h2 = u@W1+b1 relu -> H chunked
    agg(H, T, 192, 2, 0, 0, 0);             // A2: u = A h2          -> T row
    gemm(T, 2, H, 192, 256, 1, 1, 0);       // G2: h3 = u@W2+b2 relu -> H row
    gemm(H, 3, T, 256, 256, 0, 0, 1);       // G3: t = h3@W3         -> T chunked
    agg(T, H, 256, 3, 1, 1, 0);             // A3: h4 = At+b3 relu   -> H row
    gemm(H, 4, T, 256, 256, 0, 0, 1);       // G4: t = h4@W4         -> T chunked
    agg(T, H, 256, 4, 1, 0, 0);             // A4: h5 = At+b4        -> H row
    gemm(H, 5, T, 256, 256, 0, 0, 1);       // G5: t = h5@W5         -> T chunked
    agg(T, H, 256, 5, 1, 1, 0);             // A5: h6 = At+b5 relu   -> H row
    gemm(H, 6, T, 256, 192, 0, 0, 1);       // G6: t = h6@W6         -> T chunked
    agg(T, H, 192, 6, 1, 1, 0);             // A6: h7 = At+b6 relu   -> H row
    gemm(H, 7, T, 192, 128, 0, 0, 1);       // G7: t = h7@W7         -> T chunked
    agg(T, H, 128, 7, 1, 1, 0);             // A7: h8 = At+b7 relu   -> H row
    gemv128_bf16_kernel<<<(Nn + 3) / 4, 256, 0, stream>>>(H, (const float*)d_in[2 + 16],
                                                          F, Nn);
    agg1_kernel<<<nbN, TPB, 0, stream>>>(F, rowp, cnt, edges, (const float*)d_in[3 + 16],
                                         (float*)d_out, Nn, 0);
}

// Round 6
// 926.875 us; speedup vs baseline: 1.4181x; 1.4181x over previous
//
#include <hip/hip_runtime.h>

// ---------------------------------------------------------------------------
// GCN stack: 9 layers of  h = relu( Â (h W) + b ),  Â = D^-1/2 (A+I) D^-1/2
//   * Â(HW) == (ÂH)W  -> aggregate at width min(din,dout) per layer
//   * Â identical across layers -> CSR (self-loops folded) built once
// R6: chunk-major XCD-pinned aggregation (R5's locality: FETCH 188->38 MB)
//     with group-per-dst-node execution (R4's amortization): wave = 8 dst
//     nodes x 8 lanes, each group sweeps its node's full edge list, no
//     reduction tree. 2x unrolled independent edge->row chains.
// ---------------------------------------------------------------------------

#define TPB 256

using bf16x8 = __attribute__((ext_vector_type(8))) __bf16;
using f32x4  = __attribute__((ext_vector_type(4))) float;

__device__ __forceinline__ unsigned bf16rne(float x) {
    unsigned u = __float_as_uint(x);
    return (u + 0x7fffu + ((u >> 16) & 1u)) >> 16;
}

// async global->LDS, 16B per lane. l is the WAVE-UNIFORM base; HW adds lane*16.
__device__ __forceinline__ void stage16(const unsigned short* g, unsigned short* l) {
#if __has_builtin(__builtin_amdgcn_global_load_lds)
    __builtin_amdgcn_global_load_lds((const __attribute__((address_space(1))) void*)g,
                                     (__attribute__((address_space(3))) void*)l, 16, 0, 0);
#else
    *(uint4*)((char*)l + (threadIdx.x & 63) * 16) = *(const uint4*)g;
#endif
}

// ---------------- graph prep kernels ----------------

__global__ void zero_int_kernel(int* p, int n) {
    int i = blockIdx.x * blockDim.x + threadIdx.x;
    if (i < n) p[i] = 0;
}

__global__ void count_kernel(const int* __restrict__ dst, int* __restrict__ cnt, int E) {
    int e = blockIdx.x * blockDim.x + threadIdx.x;
    if (e < E) atomicAdd(&cnt[dst[e]], 1);
}

__global__ void dinv_kernel(const int* __restrict__ cnt, float* __restrict__ dinv, int n) {
    int i = blockIdx.x * blockDim.x + threadIdx.x;
    if (i < n) dinv[i] = rsqrtf((float)(cnt[i] + 1));
}

__global__ void scan1_kernel(const int* __restrict__ cnt, int* __restrict__ rowp,
                             int* __restrict__ bsums, int n) {
    __shared__ int sh[TPB];
    int t = threadIdx.x;
    int i = blockIdx.x * TPB + t;
    int v = (i < n) ? (cnt[i] + 1) : 0;       // +1 self loop in CSR
    sh[t] = v;
    __syncthreads();
    for (int off = 1; off < TPB; off <<= 1) {
        int x = (t >= off) ? sh[t - off] : 0;
        __syncthreads();
        sh[t] += x;
        __syncthreads();
    }
    if (i < n) rowp[i] = sh[t] - v;
    if (t == TPB - 1) bsums[blockIdx.x] = sh[t];
}

__global__ void scan2_kernel(int* __restrict__ bsums, int nb) {
    __shared__ int sh[TPB];
    int t = threadIdx.x;
    int v = (t < nb) ? bsums[t] : 0;
    sh[t] = v;
    __syncthreads();
    for (int off = 1; off < TPB; off <<= 1) {
        int x = (t >= off) ? sh[t - off] : 0;
        __syncthreads();
        sh[t] += x;
        __syncthreads();
    }
    if (t < nb) bsums[t] = sh[t] - v;
}

__global__ void scan3_kernel(int* __restrict__ rowp, const int* __restrict__ bsums, int n) {
    int i = blockIdx.x * TPB + threadIdx.x;
    if (i < n) rowp[i] += bsums[blockIdx.x];
}

// edge = u16 src | bf16(weight) << 16   (N=50000 < 65536)
__global__ void fill_kernel(const int* __restrict__ src, const int* __restrict__ dst,
                            const float* __restrict__ dinv,
                            const int* __restrict__ rowp, int* __restrict__ fill,
                            unsigned* __restrict__ edges, int E) {
    int e = blockIdx.x * blockDim.x + threadIdx.x;
    if (e >= E) return;
    int s = src[e], d = dst[e];
    int pos = rowp[d] + atomicAdd(&fill[d], 1);
    edges[pos] = (unsigned)s | (bf16rne(dinv[s] * dinv[d]) << 16);
}

__global__ void self_kernel(const int* __restrict__ cnt, const int* __restrict__ rowp,
                            const float* __restrict__ dinv, unsigned* __restrict__ edges,
                            int n) {
    int i = blockIdx.x * blockDim.x + threadIdx.x;
    if (i >= n) return;
    float dv = dinv[i];
    edges[rowp[i] + cnt[i]] = (unsigned)i | (bf16rne(dv * dv) << 16);
}

// ---------------- weight / input prep ----------------

__global__ void wt_kernel(const float* __restrict__ W, unsigned short* __restrict__ Wt,
                          int K, int N) {
    int id = blockIdx.x * blockDim.x + threadIdx.x;
    if (id >= K * N) return;
    int k = id / N, n = id % N;
    Wt[n * K + k] = (unsigned short)bf16rne(W[id]);
}

__global__ void cvt_bf16_kernel(const float* __restrict__ in, unsigned short* __restrict__ out,
                                int n4) {
    int i = blockIdx.x * blockDim.x + threadIdx.x;
    if (i >= n4) return;
    float4 v = ((const float4*)in)[i];
    uint2 o;
    o.x = bf16rne(v.x) | (bf16rne(v.y) << 16);
    o.y = bf16rne(v.z) | (bf16rne(v.w) << 16);
    ((uint2*)out)[i] = o;
}

// ---------------- MFMA GEMM ----------------

// C[M,Nc] = A[M,K] @ W[K,Nc] (+bias,relu). A bf16 row-major, Wt bf16 [Nc][K].
// 128x128 block tile, 4 waves, each 4x4 tiles of 16x16x32 MFMA. K%32==0.
// Output bf16: row-major or chunk-major ([gc/32][gr][gc%32]).
__global__ __launch_bounds__(256) void gemm_mfma_kernel(
    const unsigned short* __restrict__ A, const unsigned short* __restrict__ Wt,
    const float* __restrict__ bias, unsigned short* __restrict__ C,
    int M, int K, int Nc, int doBias, int doRelu, int outChunked) {
    __shared__ unsigned short Ab[128 * 32];
    __shared__ unsigned short Bb[128 * 32];
    int tid = threadIdx.x;
    int l = tid & 63, w = tid >> 6;
    int row0 = blockIdx.y * 128, col0 = blockIdx.x * 128;

    f32x4 acc[4][4];
#pragma unroll
    for (int i = 0; i < 4; i++)
#pragma unroll
        for (int j = 0; j < 4; j++) acc[i][j] = (f32x4){0.f, 0.f, 0.f, 0.f};

    const unsigned short* gA[2];
    const unsigned short* gB[2];
    unsigned short* lA[2];
    unsigned short* lB[2];
#pragma unroll
    for (int h = 0; h < 2; h++) {
        int slot = tid + h * 256;
        int r = slot >> 2, q = slot & 3;
        int ar = row0 + r; if (ar > M - 1) ar = M - 1;
        int bn = col0 + r; if (bn > Nc - 1) bn = Nc - 1;
        gA[h] = A + (size_t)ar * K + q * 8;
        gB[h] = Wt + (size_t)bn * K + q * 8;
        lA[h] = Ab + (size_t)(w * 64 + h * 256) * 8;
        lB[h] = Bb + (size_t)(w * 64 + h * 256) * 8;
    }

    int q4 = l >> 4, m16 = l & 15;
    const unsigned short* ap[4];
    const unsigned short* bp[4];
#pragma unroll
    for (int i = 0; i < 4; i++) {
        int rA = (w & 1) * 64 + i * 16 + m16;
        int rB = (w >> 1) * 64 + i * 16 + m16;
        ap[i] = Ab + rA * 32 + q4 * 8;
        bp[i] = Bb + rB * 32 + q4 * 8;
    }

    for (int k0 = 0; k0 < K; k0 += 32) {
        __syncthreads();
#pragma unroll
        for (int h = 0; h < 2; h++) {
            stage16(gA[h] + k0, lA[h]);
            stage16(gB[h] + k0, lB[h]);
        }
        __syncthreads();
        bf16x8 af[4], bfr[4];
#pragma unroll
        for (int i = 0; i < 4; i++) af[i] = *(const bf16x8*)ap[i];
#pragma unroll
        for (int j = 0; j < 4; j++) bfr[j] = *(const bf16x8*)bp[j];
#pragma unroll
        for (int i = 0; i < 4; i++)
#pragma unroll
            for (int j = 0; j < 4; j++)
                acc[i][j] = __builtin_amdgcn_mfma_f32_16x16x32_bf16(af[i], bfr[j],
                                                                    acc[i][j], 0, 0, 0);
    }

    // C/D layout: col=lane&15, row=quad*4+reg
#pragma unroll
    for (int j = 0; j < 4; j++) {
        int gc = col0 + (w >> 1) * 64 + j * 16 + m16;
        if (gc >= Nc) continue;
        float bv = doBias ? bias[gc] : 0.f;
        size_t cbase = outChunked ? ((size_t)(gc >> 5) * ((size_t)M * 32) + (gc & 31))
                                  : (size_t)gc;
#pragma unroll
        for (int i = 0; i < 4; i++) {
            int gr0 = row0 + (w & 1) * 64 + i * 16 + q4 * 4;
            f32x4 v = acc[i][j];
#pragma unroll
            for (int reg = 0; reg < 4; reg++) {
                int gr = gr0 + reg;
                if (gr >= M) continue;
                float x = v[reg] + bv;
                if (doRelu) x = fmaxf(x, 0.f);
                size_t off = outChunked ? (cbase + (size_t)gr * 32)
                                        : (cbase + (size_t)gr * Nc);
                C[off] = (unsigned short)bf16rne(x);
            }
        }
    }
}

// out[m] = dot(A[m,0:128], w[0:128])  A bf16 row-major, one wave per row
__global__ void gemv128_bf16_kernel(const unsigned short* __restrict__ A,
                                    const float* __restrict__ w,
                                    float* __restrict__ out, int M) {
    int wid = (blockIdx.x * blockDim.x + threadIdx.x) >> 6;
    int lane = threadIdx.x & 63;
    if (wid >= M) return;
    const unsigned short* a = A + (size_t)wid * 128;
    float a0 = __uint_as_float((unsigned)a[lane] << 16);
    float a1 = __uint_as_float((unsigned)a[lane + 64] << 16);
    float s = a0 * w[lane] + a1 * w[lane + 64];
#pragma unroll
    for (int off = 32; off > 0; off >>= 1) s += __shfl_down(s, off);
    if (lane == 0) out[wid] = s;
}

// ---------------- chunked aggregation, group-per-node ----------------

// Input: bf16 chunk-major [chunk][node][32f] (3.2 MB slice per chunk).
// Wave = 8 dst nodes x 8 lanes. Each 8-lane group sweeps its node's full edge
// list; lane fl covers feats [4fl,4fl+4) as uint2. No cross-group reduction.
// blockIdx%8 = XCD; xcd->(chunk, shareIdx) map keeps each XCD's gather working
// set to one 3.2 MB slice (L2-resident).
__global__ __launch_bounds__(256) void agg_group_kernel(
    const uint2* __restrict__ in, const int* __restrict__ rowp,
    const int* __restrict__ cnt, const unsigned* __restrict__ edges,
    const float* __restrict__ bias, uint2* __restrict__ out,
    int nchunks, int NG /*node groups of 32*/, int n_nodes, int rowVec2,
    int doBias, int doRelu, int outChunked) {
    int xcd = blockIdx.x & 7;
    int slot = blockIdx.x >> 3;
    // xcd -> (chunk, shareIdx, shareCnt): working set = 1 slice per XCD
    int chunk, shareIdx, shareCnt;
    if (nchunks == 8) { chunk = xcd; shareIdx = 0; shareCnt = 1; }
    else if (nchunks == 4) { chunk = xcd >> 1; shareIdx = xcd & 1; shareCnt = 2; }
    else {  // nchunks == 6: chunks 0,1 split across xcds {0,6} and {1,7}
        chunk = (xcd < 6) ? xcd : (xcd - 6);
        if (chunk < 2) { shareCnt = 2; shareIdx = (xcd < 6) ? 0 : 1; }
        else { shareCnt = 1; shareIdx = 0; }
    }
    int ngPerShare = (NG + shareCnt - 1) / shareCnt;
    if (slot >= ngPerShare) return;
    int ng = shareIdx * ngPerShare + slot;
    if (ng >= NG) return;

    int wave = threadIdx.x >> 6;
    int lane = threadIdx.x & 63;
    int group = lane >> 3, fl = lane & 7;
    int node = ng * 32 + wave * 8 + group;
    if (node >= n_nodes) return;

    const uint2* slice = in + (size_t)chunk * n_nodes * 8;
    int s0 = rowp[node];
    int c = cnt[node] + 1;

    float ax0 = 0.f, ay0 = 0.f, az0 = 0.f, aw0 = 0.f;
    float ax1 = 0.f, ay1 = 0.f, az1 = 0.f, aw1 = 0.f;
    int j = 0;
    for (; j + 2 <= c; j += 2) {
        unsigned e0 = edges[s0 + j];
        unsigned e1 = edges[s0 + j + 1];
        uint2 p0 = slice[(e0 & 0xffffu) * 8 + fl];
        uint2 p1 = slice[(e1 & 0xffffu) * 8 + fl];
        float w0 = __uint_as_float(e0 & 0xffff0000u);
        float w1 = __uint_as_float(e1 & 0xffff0000u);
        ax0 += w0 * __uint_as_float(p0.x << 16);
        ay0 += w0 * __uint_as_float(p0.x & 0xffff0000u);
        az0 += w0 * __uint_as_float(p0.y << 16);
        aw0 += w0 * __uint_as_float(p0.y & 0xffff0000u);
        ax1 += w1 * __uint_as_float(p1.x << 16);
        ay1 += w1 * __uint_as_float(p1.x & 0xffff0000u);
        az1 += w1 * __uint_as_float(p1.y << 16);
        aw1 += w1 * __uint_as_float(p1.y & 0xffff0000u);
    }
    if (j < c) {
        unsigned e0 = edges[s0 + j];
        uint2 p0 = slice[(e0 & 0xffffu) * 8 + fl];
        float w0 = __uint_as_float(e0 & 0xffff0000u);
        ax0 += w0 * __uint_as_float(p0.x << 16);
        ay0 += w0 * __uint_as_float(p0.x & 0xffff0000u);
        az0 += w0 * __uint_as_float(p0.y << 16);
        aw0 += w0 * __uint_as_float(p0.y & 0xffff0000u);
    }
    float ax = ax0 + ax1, ay = ay0 + ay1, az = az0 + az1, aw = aw0 + aw1;

    if (doBias) {
        float4 bb = ((const float4*)bias)[chunk * 8 + fl];
        ax += bb.x; ay += bb.y; az += bb.z; aw += bb.w;
    }
    if (doRelu) {
        ax = fmaxf(ax, 0.f); ay = fmaxf(ay, 0.f);
        az = fmaxf(az, 0.f); aw = fmaxf(aw, 0.f);
    }
    uint2 o;
    o.x = bf16rne(ax) | (bf16rne(ay) << 16);
    o.y = bf16rne(az) | (bf16rne(aw) << 16);
    size_t oi = outChunked ? ((size_t)chunk * n_nodes * 8 + (size_t)node * 8 + fl)
                           : ((size_t)node * rowVec2 + chunk * 8 + fl);
    out[oi] = o;
}

// width-1 aggregation, fp32: one thread per node
__global__ void agg1_kernel(const float* __restrict__ in, const int* __restrict__ rowp,
                            const int* __restrict__ cnt, const unsigned* __restrict__ edges,
                            const float* __restrict__ bias, float* __restrict__ out,
                            int n_nodes, int doRelu) {
    int n = blockIdx.x * blockDim.x + threadIdx.x;
    if (n >= n_nodes) return;
    float acc = 0.f;
    int s0 = rowp[n];
    int c = cnt[n] + 1;
    for (int j = 0; j < c; j++) {
        unsigned e = edges[s0 + j];
        acc += __uint_as_float(e & 0xffff0000u) * in[e & 0xffffu];
    }
    acc += bias[0];
    if (doRelu) acc = fmaxf(acc, 0.f);
    out[n] = acc;
}

// ---------------- host launcher ----------------

extern "C" void kernel_launch(void* const* d_in, const int* in_sizes, int n_in,
                              void* d_out, int out_size, void* d_ws, size_t ws_size,
                              hipStream_t stream) {
    const float* x = (const float*)d_in[0];
    const int* ei = (const int*)d_in[1];
    const int Nn = in_sizes[0] / 128;      // 50000
    const int E = in_sizes[1] / 2;         // 800000
    const int* src = ei;
    const int* dst = ei + E;

    char* ws = (char*)d_ws;
    size_t off = 0;
    auto alloc = [&](size_t bytes) -> char* {
        char* p = ws + off;
        off = (off + bytes + 255) & ~(size_t)255;
        return p;
    };
    int* cnt = (int*)alloc((size_t)Nn * 4);
    int* fill = (int*)alloc((size_t)Nn * 4);
    int* rowp = (int*)alloc((size_t)Nn * 4);
    int* bsums = (int*)alloc(1024);
    float* dinv = (float*)alloc((size_t)Nn * 4);
    unsigned* edges = (unsigned*)alloc((size_t)(E + Nn) * 4);
    unsigned short* T = (unsigned short*)alloc((size_t)Nn * 256 * 2);
    unsigned short* H = (unsigned short*)alloc((size_t)Nn * 256 * 2);
    unsigned short* Bx = (unsigned short*)alloc((size_t)Nn * 128 * 2);
    float* F = (float*)alloc((size_t)Nn * 4);
    unsigned short* Wts = (unsigned short*)alloc((size_t)400000 * 2);
    (void)ws_size;

    const int dims[9][2] = {{128,128},{128,192},{192,256},{256,256},{256,256},
                            {256,256},{256,192},{192,128},{128,1}};
    unsigned short* Wt[8];
    {
        size_t o = 0;
        for (int i = 0; i < 8; i++) { Wt[i] = Wts + o; o += (size_t)dims[i][0] * dims[i][1]; }
    }

    int nbN = (Nn + TPB - 1) / TPB;
    int nbE = (E + TPB - 1) / TPB;

    // ---- graph prep ----
    zero_int_kernel<<<nbN, TPB, 0, stream>>>(cnt, Nn);
    zero_int_kernel<<<nbN, TPB, 0, stream>>>(fill, Nn);
    count_kernel<<<nbE, TPB, 0, stream>>>(dst, cnt, E);
    dinv_kernel<<<nbN, TPB, 0, stream>>>(cnt, dinv, Nn);
    scan1_kernel<<<nbN, TPB, 0, stream>>>(cnt, rowp, bsums, Nn);
    scan2_kernel<<<1, TPB, 0, stream>>>(bsums, nbN);
    scan3_kernel<<<nbN, TPB, 0, stream>>>(rowp, bsums, Nn);
    fill_kernel<<<nbE, TPB, 0, stream>>>(src, dst, dinv, rowp, fill, edges, E);
    self_kernel<<<nbN, TPB, 0, stream>>>(cnt, rowp, dinv, edges, Nn);

    // ---- weight transpose + input convert ----
    for (int i = 0; i < 8; i++) {
        int K = dims[i][0], N = dims[i][1];
        wt_kernel<<<(K * N + TPB - 1) / TPB, TPB, 0, stream>>>(
            (const float*)d_in[2 + 2 * i], Wt[i], K, N);
    }
    cvt_bf16_kernel<<<(Nn * 32 + TPB - 1) / TPB, TPB, 0, stream>>>(x, Bx, Nn * 32);

    auto gemm = [&](const unsigned short* A, int i, unsigned short* C, int K, int Nc,
                    int doBias, int doRelu, int outChunked) {
        const float* b = (const float*)d_in[3 + 2 * i];
        dim3 grid((Nc + 127) / 128, (Nn + 127) / 128);
        gemm_mfma_kernel<<<grid, 256, 0, stream>>>(A, Wt[i], b, C, Nn, K, Nc,
                                                   doBias, doRelu, outChunked);
    };
    int NG = (Nn + 31) / 32;               // node groups of 32 (block = 32 nodes)
    auto agg = [&](const unsigned short* inb, unsigned short* outb, int w, int i,
                   int doBias, int doRelu, int outChunked) {
        int nch = w / 32;
        int blocksPerXcd = (nch == 4) ? (NG + 1) / 2 : NG;
        const float* b = (const float*)d_in[3 + 2 * i];
        agg_group_kernel<<<blocksPerXcd * 8, 256, 0, stream>>>(
            (const uint2*)inb, rowp, cnt, edges, b, (uint2*)outb,
            nch, NG, Nn, w / 4, doBias, doRelu, outChunked);
    };

    // layout chain: GEMM in=row, out=chunked (except G2: row); agg in=chunked,
    // out=row (except A0: chunked, feeds A1)
    gemm(Bx, 0, T, 128, 128, 0, 0, 1);      // G0: t = x@W0          -> T chunked
    agg(T, H, 128, 0, 1, 1, 1);             // A0: h1 = At+b0 relu   -> H chunked
    agg(H, T, 128, 1, 0, 0, 0);             // A1: u = A h1          -> T row
    gemm(T, 1, H, 128, 192, 1, 1, 1);       // G1: h2 = u@W1+b1 relu -> H chunked
    agg(H, T, 192, 2, 0, 0, 0);             // A2: u = A h2          -> T row
    gemm(T, 2, H, 192, 256, 1, 1, 0);       // G2: h3 = u@W2+b2 relu -> H row
    gemm(H, 3, T, 256, 256, 0, 0, 1);       // G3: t = h3@W3         -> T chunked
    agg(T, H, 256, 3, 1, 1, 0);             // A3: h4 = At+b3 relu   -> H row
    gemm(H, 4, T, 256, 256, 0, 0, 1);       // G4: t = h4@W4         -> T chunked
    agg(T, H, 256, 4, 1, 0, 0);             // A4: h5 = At+b4        -> H row
    gemm(H, 5, T, 256, 256, 0, 0, 1);       // G5: t = h5@W5         -> T chunked
    agg(T, H, 256, 5, 1, 1, 0);             // A5: h6 = At+b5 relu   -> H row
    gemm(H, 6, T, 256, 192, 0, 0, 1);       // G6: t = h6@W6         -> T chunked
    agg(T, H, 192, 6, 1, 1, 0);             // A6: h7 = At+b6 relu   -> H row
    gemm(H, 7, T, 192, 128, 0, 0, 1);       // G7: t = h7@W7         -> T chunked
    agg(T, H, 128, 7, 1, 1, 0);             // A7: h8 = At+b7 relu   -> H row
    gemv128_bf16_kernel<<<(Nn + 3) / 4, 256, 0, stream>>>(H, (const float*)d_in[2 + 16],
                                                          F, Nn);
    agg1_kernel<<<nbN, TPB, 0, stream>>>(F, rowp, cnt, edges, (const float*)d_in[3 + 16],
                                         (float*)d_out, Nn, 0);
}

// Round 7
// 769.054 us; speedup vs baseline: 1.7091x; 1.2052x over previous
//
#include <hip/hip_runtime.h>

// ---------------------------------------------------------------------------
// GCN stack: 9 layers of  h = relu( Â (h W) + b ),  Â = D^-1/2 (A+I) D^-1/2
//   * Â(HW) == (ÂH)W  -> aggregate at width min(din,dout) per layer
//   * Â identical across layers -> CSR (self-loops folded) built once
// R7: (a) agg: group-wide edge prefetch (1 coalesced load + shfl broadcast)
//     + fully-unrolled 8 independent row gathers -> breaks the edge->row
//     latency chain that bound R6. Chunk layout + XCD pinning kept.
//     (b) GEMM: XOR-swizzled LDS (swizzle on the GLOBAL side of stage16, LDS
//     stays linear so global_load_lds stays legal) kills the 8-way b128 bank
//     conflict; BK=64 halves barrier count.
// ---------------------------------------------------------------------------

#define TPB 256

using bf16x8 = __attribute__((ext_vector_type(8))) __bf16;
using f32x4  = __attribute__((ext_vector_type(4))) float;

__device__ __forceinline__ unsigned bf16rne(float x) {
    unsigned u = __float_as_uint(x);
    return (u + 0x7fffu + ((u >> 16) & 1u)) >> 16;
}

// async global->LDS, 16B per lane. l is the WAVE-UNIFORM base; HW adds lane*16.
__device__ __forceinline__ void stage16(const unsigned short* g, unsigned short* l) {
#if __has_builtin(__builtin_amdgcn_global_load_lds)
    __builtin_amdgcn_global_load_lds((const __attribute__((address_space(1))) void*)g,
                                     (__attribute__((address_space(3))) void*)l, 16, 0, 0);
#else
    *(uint4*)((char*)l + (threadIdx.x & 63) * 16) = *(const uint4*)g;
#endif
}

// ---------------- graph prep kernels ----------------

__global__ void zero_int_kernel(int* p, int n) {
    int i = blockIdx.x * blockDim.x + threadIdx.x;
    if (i < n) p[i] = 0;
}

__global__ void count_kernel(const int* __restrict__ dst, int* __restrict__ cnt, int E) {
    int e = blockIdx.x * blockDim.x + threadIdx.x;
    if (e < E) atomicAdd(&cnt[dst[e]], 1);
}

__global__ void dinv_kernel(const int* __restrict__ cnt, float* __restrict__ dinv, int n) {
    int i = blockIdx.x * blockDim.x + threadIdx.x;
    if (i < n) dinv[i] = rsqrtf((float)(cnt[i] + 1));
}

__global__ void scan1_kernel(const int* __restrict__ cnt, int* __restrict__ rowp,
                             int* __restrict__ bsums, int n) {
    __shared__ int sh[TPB];
    int t = threadIdx.x;
    int i = blockIdx.x * TPB + t;
    int v = (i < n) ? (cnt[i] + 1) : 0;       // +1 self loop in CSR
    sh[t] = v;
    __syncthreads();
    for (int off = 1; off < TPB; off <<= 1) {
        int x = (t >= off) ? sh[t - off] : 0;
        __syncthreads();
        sh[t] += x;
        __syncthreads();
    }
    if (i < n) rowp[i] = sh[t] - v;
    if (t == TPB - 1) bsums[blockIdx.x] = sh[t];
}

__global__ void scan2_kernel(int* __restrict__ bsums, int nb) {
    __shared__ int sh[TPB];
    int t = threadIdx.x;
    int v = (t < nb) ? bsums[t] : 0;
    sh[t] = v;
    __syncthreads();
    for (int off = 1; off < TPB; off <<= 1) {
        int x = (t >= off) ? sh[t - off] : 0;
        __syncthreads();
        sh[t] += x;
        __syncthreads();
    }
    if (t < nb) bsums[t] = sh[t] - v;
}

__global__ void scan3_kernel(int* __restrict__ rowp, const int* __restrict__ bsums, int n) {
    int i = blockIdx.x * TPB + threadIdx.x;
    if (i < n) rowp[i] += bsums[blockIdx.x];
}

// edge = u16 src | bf16(weight) << 16   (N=50000 < 65536)
__global__ void fill_kernel(const int* __restrict__ src, const int* __restrict__ dst,
                            const float* __restrict__ dinv,
                            const int* __restrict__ rowp, int* __restrict__ fill,
                            unsigned* __restrict__ edges, int E) {
    int e = blockIdx.x * blockDim.x + threadIdx.x;
    if (e >= E) return;
    int s = src[e], d = dst[e];
    int pos = rowp[d] + atomicAdd(&fill[d], 1);
    edges[pos] = (unsigned)s | (bf16rne(dinv[s] * dinv[d]) << 16);
}

__global__ void self_kernel(const int* __restrict__ cnt, const int* __restrict__ rowp,
                            const float* __restrict__ dinv, unsigned* __restrict__ edges,
                            int n) {
    int i = blockIdx.x * blockDim.x + threadIdx.x;
    if (i >= n) return;
    float dv = dinv[i];
    edges[rowp[i] + cnt[i]] = (unsigned)i | (bf16rne(dv * dv) << 16);
}

// ---------------- weight / input prep ----------------

__global__ void wt_kernel(const float* __restrict__ W, unsigned short* __restrict__ Wt,
                          int K, int N) {
    int id = blockIdx.x * blockDim.x + threadIdx.x;
    if (id >= K * N) return;
    int k = id / N, n = id % N;
    Wt[n * K + k] = (unsigned short)bf16rne(W[id]);
}

__global__ void cvt_bf16_kernel(const float* __restrict__ in, unsigned short* __restrict__ out,
                                int n4) {
    int i = blockIdx.x * blockDim.x + threadIdx.x;
    if (i >= n4) return;
    float4 v = ((const float4*)in)[i];
    uint2 o;
    o.x = bf16rne(v.x) | (bf16rne(v.y) << 16);
    o.y = bf16rne(v.z) | (bf16rne(v.w) << 16);
    ((uint2*)out)[i] = o;
}

// ---------------- MFMA GEMM ----------------

// C[M,Nc] = A[M,K] @ W[K,Nc] (+bias,relu). A bf16 row-major, Wt bf16 [Nc][K].
// 128x128 tile, 4 waves x (4x4 of 16x16x32 MFMA), BK=64, K%64==0.
// LDS [row][64] linear; XOR swizzle applied on the GLOBAL side of stage16:
// LDS slot (r,q) holds global k-chunk q^(r&7)  ->  b128 fragment reads are
// bank-conflict-free, and global_load_lds contiguity is preserved.
__global__ __launch_bounds__(256) void gemm_mfma_kernel(
    const unsigned short* __restrict__ A, const unsigned short* __restrict__ Wt,
    const float* __restrict__ bias, unsigned short* __restrict__ C,
    int M, int K, int Nc, int doBias, int doRelu, int outChunked) {
    __shared__ unsigned short Ab[128 * 64];   // 16 KB
    __shared__ unsigned short Bb[128 * 64];   // 16 KB
    int tid = threadIdx.x;
    int l = tid & 63, w = tid >> 6;
    int row0 = blockIdx.y * 128, col0 = blockIdx.x * 128;

    f32x4 acc[4][4];
#pragma unroll
    for (int i = 0; i < 4; i++)
#pragma unroll
        for (int j = 0; j < 4; j++) acc[i][j] = (f32x4){0.f, 0.f, 0.f, 0.f};

    // staging: 1024 slots/array (slot = row*8 + q, 8 elems each); thread t
    // handles slots t + h*256, h=0..3. Global chunk = q ^ (r&7) (swizzle).
    const unsigned short* gA[4];
    const unsigned short* gB[4];
    unsigned short* lA[4];
    unsigned short* lB[4];
#pragma unroll
    for (int h = 0; h < 4; h++) {
        int slot = tid + h * 256;
        int r = slot >> 3, q = slot & 7;
        int qg = q ^ (r & 7);
        int ar = row0 + r; if (ar > M - 1) ar = M - 1;
        int bn = col0 + r; if (bn > Nc - 1) bn = Nc - 1;
        gA[h] = A + (size_t)ar * K + qg * 8;
        gB[h] = Wt + (size_t)bn * K + qg * 8;
        lA[h] = Ab + (size_t)(w * 64 + h * 256) * 8;   // wave-uniform base
        lB[h] = Bb + (size_t)(w * 64 + h * 256) * 8;
    }

    int q4 = l >> 4, m16 = l & 15;
    int rA0 = (w & 1) * 64 + m16;
    int rB0 = (w >> 1) * 64 + m16;
    int sw = m16 & 7;                          // row-dependent swizzle key

    for (int k0 = 0; k0 < K; k0 += 64) {
        __syncthreads();                       // prior reads done
#pragma unroll
        for (int h = 0; h < 4; h++) {
            stage16(gA[h] + k0, lA[h]);
            stage16(gB[h] + k0, lB[h]);
        }
        __syncthreads();                       // staging complete
#pragma unroll
        for (int ko = 0; ko < 2; ko++) {
            bf16x8 af[4], bfr[4];
#pragma unroll
            for (int i = 0; i < 4; i++) {
                int r = rA0 + i * 16;
                af[i] = *(const bf16x8*)(Ab + r * 64 + ((ko * 4 + q4) ^ sw) * 8);
            }
#pragma unroll
            for (int j = 0; j < 4; j++) {
                int r = rB0 + j * 16;
                bfr[j] = *(const bf16x8*)(Bb + r * 64 + ((ko * 4 + q4) ^ sw) * 8);
            }
#pragma unroll
            for (int i = 0; i < 4; i++)
#pragma unroll
                for (int j = 0; j < 4; j++)
                    acc[i][j] = __builtin_amdgcn_mfma_f32_16x16x32_bf16(af[i], bfr[j],
                                                                        acc[i][j], 0, 0, 0);
        }
    }

    // C/D layout: col=lane&15, row=quad*4+reg
#pragma unroll
    for (int j = 0; j < 4; j++) {
        int gc = col0 + (w >> 1) * 64 + j * 16 + m16;
        if (gc >= Nc) continue;
        float bv = doBias ? bias[gc] : 0.f;
        size_t cbase = outChunked ? ((size_t)(gc >> 5) * ((size_t)M * 32) + (gc & 31))
                                  : (size_t)gc;
#pragma unroll
        for (int i = 0; i < 4; i++) {
            int gr0 = row0 + (w & 1) * 64 + i * 16 + q4 * 4;
            f32x4 v = acc[i][j];
#pragma unroll
            for (int reg = 0; reg < 4; reg++) {
                int gr = gr0 + reg;
                if (gr >= M) continue;
                float x = v[reg] + bv;
                if (doRelu) x = fmaxf(x, 0.f);
                size_t off = outChunked ? (cbase + (size_t)gr * 32)
                                        : (cbase + (size_t)gr * Nc);
                C[off] = (unsigned short)bf16rne(x);
            }
        }
    }
}

// out[m] = dot(A[m,0:128], w[0:128])  A bf16 row-major, one wave per row
__global__ void gemv128_bf16_kernel(const unsigned short* __restrict__ A,
                                    const float* __restrict__ w,
                                    float* __restrict__ out, int M) {
    int wid = (blockIdx.x * blockDim.x + threadIdx.x) >> 6;
    int lane = threadIdx.x & 63;
    if (wid >= M) return;
    const unsigned short* a = A + (size_t)wid * 128;
    float a0 = __uint_as_float((unsigned)a[lane] << 16);
    float a1 = __uint_as_float((unsigned)a[lane + 64] << 16);
    float s = a0 * w[lane] + a1 * w[lane + 64];
#pragma unroll
    for (int off = 32; off > 0; off >>= 1) s += __shfl_down(s, off);
    if (lane == 0) out[wid] = s;
}

// ---------------- chunked aggregation, group-per-node ----------------

// Input: bf16 chunk-major [chunk][node][32f] (3.2 MB slice per chunk).
// Wave = 8 dst nodes x 8 lanes. Per 8-edge block: lane fl prefetches
// edges[s0+base+fl] (one coalesced load), shfl broadcasts within the group,
// then 8 INDEPENDENT row gathers issue together (zero-weight padding, no
// inner guards). blockIdx%8 = XCD; chunk pinned per XCD (L2-resident slice).
__global__ __launch_bounds__(256) void agg_group_kernel(
    const uint2* __restrict__ in, const int* __restrict__ rowp,
    const int* __restrict__ cnt, const unsigned* __restrict__ edges,
    const float* __restrict__ bias, uint2* __restrict__ out,
    int nchunks, int NG /*node groups of 32*/, int n_nodes, int rowVec2,
    int doBias, int doRelu, int outChunked) {
    int xcd = blockIdx.x & 7;
    int slot = blockIdx.x >> 3;
    int chunk, shareIdx, shareCnt;
    if (nchunks == 8) { chunk = xcd; shareIdx = 0; shareCnt = 1; }
    else if (nchunks == 4) { chunk = xcd >> 1; shareIdx = xcd & 1; shareCnt = 2; }
    else {  // nchunks == 6: chunks 0,1 split across xcds {0,6} and {1,7}
        chunk = (xcd < 6) ? xcd : (xcd - 6);
        if (chunk < 2) { shareCnt = 2; shareIdx = (xcd < 6) ? 0 : 1; }
        else { shareCnt = 1; shareIdx = 0; }
    }
    int ngPerShare = (NG + shareCnt - 1) / shareCnt;
    if (slot >= ngPerShare) return;
    int ng = shareIdx * ngPerShare + slot;
    if (ng >= NG) return;

    int wave = threadIdx.x >> 6;
    int lane = threadIdx.x & 63;
    int group = lane >> 3, fl = lane & 7;
    int gb = lane & ~7;                        // group's base lane
    int node = ng * 32 + wave * 8 + group;
    if (node >= n_nodes) return;

    const uint2* slice = in + (size_t)chunk * n_nodes * 8;
    int s0 = rowp[node];
    int c = cnt[node] + 1;

    float ax0 = 0.f, ay0 = 0.f, az0 = 0.f, aw0 = 0.f;
    float ax1 = 0.f, ay1 = 0.f, az1 = 0.f, aw1 = 0.f;

    for (int base = 0; base < c; base += 8) {
        int idx = base + fl;
        unsigned ew = (idx < c) ? edges[s0 + idx] : 0u;   // pad: src 0, w +0.0
#pragma unroll
        for (int j = 0; j < 8; j += 2) {
            unsigned e0 = (unsigned)__shfl((int)ew, gb + j);
            unsigned e1 = (unsigned)__shfl((int)ew, gb + j + 1);
            uint2 p0 = slice[(int)(e0 & 0xffffu) * 8 + fl];
            uint2 p1 = slice[(int)(e1 & 0xffffu) * 8 + fl];
            float w0 = __uint_as_float(e0 & 0xffff0000u);
            float w1 = __uint_as_float(e1 & 0xffff0000u);
            ax0 += w0 * __uint_as_float(p0.x << 16);
            ay0 += w0 * __uint_as_float(p0.x & 0xffff0000u);
            az0 += w0 * __uint_as_float(p0.y << 16);
            aw0 += w0 * __uint_as_float(p0.y & 0xffff0000u);
            ax1 += w1 * __uint_as_float(p1.x << 16);
            ay1 += w1 * __uint_as_float(p1.x & 0xffff0000u);
            az1 += w1 * __uint_as_float(p1.y << 16);
            aw1 += w1 * __uint_as_float(p1.y & 0xffff0000u);
        }
    }
    float ax = ax0 + ax1, ay = ay0 + ay1, az = az0 + az1, aw = aw0 + aw1;

    if (doBias) {
        float4 bb = ((const float4*)bias)[chunk * 8 + fl];
        ax += bb.x; ay += bb.y; az += bb.z; aw += bb.w;
    }
    if (doRelu) {
        ax = fmaxf(ax, 0.f); ay = fmaxf(ay, 0.f);
        az = fmaxf(az, 0.f); aw = fmaxf(aw, 0.f);
    }
    uint2 o;
    o.x = bf16rne(ax) | (bf16rne(ay) << 16);
    o.y = bf16rne(az) | (bf16rne(aw) << 16);
    size_t oi = outChunked ? ((size_t)chunk * n_nodes * 8 + (size_t)node * 8 + fl)
                           : ((size_t)node * rowVec2 + chunk * 8 + fl);
    out[oi] = o;
}

// width-1 aggregation, fp32: one thread per node
__global__ void agg1_kernel(const float* __restrict__ in, const int* __restrict__ rowp,
                            const int* __restrict__ cnt, const unsigned* __restrict__ edges,
                            const float* __restrict__ bias, float* __restrict__ out,
                            int n_nodes, int doRelu) {
    int n = blockIdx.x * blockDim.x + threadIdx.x;
    if (n >= n_nodes) return;
    float acc = 0.f;
    int s0 = rowp[n];
    int c = cnt[n] + 1;
    for (int j = 0; j < c; j++) {
        unsigned e = edges[s0 + j];
        acc += __uint_as_float(e & 0xffff0000u) * in[e & 0xffffu];
    }
    acc += bias[0];
    if (doRelu) acc = fmaxf(acc, 0.f);
    out[n] = acc;
}

// ---------------- host launcher ----------------

extern "C" void kernel_launch(void* const* d_in, const int* in_sizes, int n_in,
                              void* d_out, int out_size, void* d_ws, size_t ws_size,
                              hipStream_t stream) {
    const float* x = (const float*)d_in[0];
    const int* ei = (const int*)d_in[1];
    const int Nn = in_sizes[0] / 128;      // 50000
    const int E = in_sizes[1] / 2;         // 800000
    const int* src = ei;
    const int* dst = ei + E;

    char* ws = (char*)d_ws;
    size_t off = 0;
    auto alloc = [&](size_t bytes) -> char* {
        char* p = ws + off;
        off = (off + bytes + 255) & ~(size_t)255;
        return p;
    };
    int* cnt = (int*)alloc((size_t)Nn * 4);
    int* fill = (int*)alloc((size_t)Nn * 4);
    int* rowp = (int*)alloc((size_t)Nn * 4);
    int* bsums = (int*)alloc(1024);
    float* dinv = (float*)alloc((size_t)Nn * 4);
    unsigned* edges = (unsigned*)alloc((size_t)(E + Nn) * 4);
    unsigned short* T = (unsigned short*)alloc((size_t)Nn * 256 * 2);
    unsigned short* H = (unsigned short*)alloc((size_t)Nn * 256 * 2);
    unsigned short* Bx = (unsigned short*)alloc((size_t)Nn * 128 * 2);
    float* F = (float*)alloc((size_t)Nn * 4);
    unsigned short* Wts = (unsigned short*)alloc((size_t)400000 * 2);
    (void)ws_size;

    const int dims[9][2] = {{128,128},{128,192},{192,256},{256,256},{256,256},
                            {256,256},{256,192},{192,128},{128,1}};
    unsigned short* Wt[8];
    {
        size_t o = 0;
        for (int i = 0; i < 8; i++) { Wt[i] = Wts + o; o += (size_t)dims[i][0] * dims[i][1]; }
    }

    int nbN = (Nn + TPB - 1) / TPB;
    int nbE = (E + TPB - 1) / TPB;

    // ---- graph prep ----
    zero_int_kernel<<<nbN, TPB, 0, stream>>>(cnt, Nn);
    zero_int_kernel<<<nbN, TPB, 0, stream>>>(fill, Nn);
    count_kernel<<<nbE, TPB, 0, stream>>>(dst, cnt, E);
    dinv_kernel<<<nbN, TPB, 0, stream>>>(cnt, dinv, Nn);
    scan1_kernel<<<nbN, TPB, 0, stream>>>(cnt, rowp, bsums, Nn);
    scan2_kernel<<<1, TPB, 0, stream>>>(bsums, nbN);
    scan3_kernel<<<nbN, TPB, 0, stream>>>(rowp, bsums, Nn);
    fill_kernel<<<nbE, TPB, 0, stream>>>(src, dst, dinv, rowp, fill, edges, E);
    self_kernel<<<nbN, TPB, 0, stream>>>(cnt, rowp, dinv, edges, Nn);

    // ---- weight transpose + input convert ----
    for (int i = 0; i < 8; i++) {
        int K = dims[i][0], N = dims[i][1];
        wt_kernel<<<(K * N + TPB - 1) / TPB, TPB, 0, stream>>>(
            (const float*)d_in[2 + 2 * i], Wt[i], K, N);
    }
    cvt_bf16_kernel<<<(Nn * 32 + TPB - 1) / TPB, TPB, 0, stream>>>(x, Bx, Nn * 32);

    auto gemm = [&](const unsigned short* A, int i, unsigned short* C, int K, int Nc,
                    int doBias, int doRelu, int outChunked) {
        const float* b = (const float*)d_in[3 + 2 * i];
        dim3 grid((Nc + 127) / 128, (Nn + 127) / 128);
        gemm_mfma_kernel<<<grid, 256, 0, stream>>>(A, Wt[i], b, C, Nn, K, Nc,
                                                   doBias, doRelu, outChunked);
    };
    int NG = (Nn + 31) / 32;               // node groups of 32 (block = 32 nodes)
    auto agg = [&](const unsigned short* inb, unsigned short* outb, int w, int i,
                   int doBias, int doRelu, int outChunked) {
        int nch = w / 32;
        int blocksPerXcd = (nch == 4) ? (NG + 1) / 2 : NG;
        const float* b = (const float*)d_in[3 + 2 * i];
        agg_group_kernel<<<blocksPerXcd * 8, 256, 0, stream>>>(
            (const uint2*)inb, rowp, cnt, edges, b, (uint2*)outb,
            nch, NG, Nn, w / 4, doBias, doRelu, outChunked);
    };

    // layout chain: GEMM in=row, out=chunked (except G2: row); agg in=chunked,
    // out=row (except A0: chunked, feeds A1)
    gemm(Bx, 0, T, 128, 128, 0, 0, 1);      // G0: t = x@W0          -> T chunked
    agg(T, H, 128, 0, 1, 1, 1);             // A0: h1 = At+b0 relu   -> H chunked
    agg(H, T, 128, 1, 0, 0, 0);             // A1: u = A h1          -> T row
    gemm(T, 1, H, 128, 192, 1, 1, 1);       // G1: h2 = u@W1+b1 relu -> H chunked
    agg(H, T, 192, 2, 0, 0, 0);             // A2: u = A h2          -> T row
    gemm(T, 2, H, 192, 256, 1, 1, 0);       // G2: h3 = u@W2+b2 relu -> H row
    gemm(H, 3, T, 256, 256, 0, 0, 1);       // G3: t = h3@W3         -> T chunked
    agg(T, H, 256, 3, 1, 1, 0);             // A3: h4 = At+b3 relu   -> H row
    gemm(H, 4, T, 256, 256, 0, 0, 1);       // G4: t = h4@W4         -> T chunked
    agg(T, H, 256, 4, 1, 0, 0);             // A4: h5 = At+b4        -> H row
    gemm(H, 5, T, 256, 256, 0, 0, 1);       // G5: t = h5@W5         -> T chunked
    agg(T, H, 256, 5, 1, 1, 0);             // A5: h6 = At+b5 relu   -> H row
    gemm(H, 6, T, 256, 192, 0, 0, 1);       // G6: t = h6@W6         -> T chunked
    agg(T, H, 192, 6, 1, 1, 0);             // A6: h7 = At+b6 relu   -> H row
    gemm(H, 7, T, 192, 128, 0, 0, 1);       // G7: t = h7@W7         -> T chunked
    agg(T, H, 128, 7, 1, 1, 0);             // A7: h8 = At+b7 relu   -> H row
    gemv128_bf16_kernel<<<(Nn + 3) / 4, 256, 0, stream>>>(H, (const float*)d_in[2 + 16],
                                                          F, Nn);
    agg1_kernel<<<nbN, TPB, 0, stream>>>(F, rowp, cnt, edges, (const float*)d_in[3 + 16],
                                         (float*)d_out, Nn, 0);
}

// Round 8
// 688.377 us; speedup vs baseline: 1.9094x; 1.1172x over previous
//
#include <hip/hip_runtime.h>

// ---------------------------------------------------------------------------
// GCN stack: 9 layers of  h = relu( Â (h W) + b ),  Â = D^-1/2 (A+I) D^-1/2
//   * Â(HW) == (ÂH)W  -> aggregate at width min(din,dout) per layer
//   * Â identical across layers -> CSR (self-loops folded) built once
// R8: (a) GEMM operand swap: A-op=weights, B-op=acts -> acc regs hold 4
//     consecutive FEATS of one node -> b64 packed stores (4x fewer), float4
//     bias. (b) agg: edge double-buffer prefetch + batched 8-gather issue,
//     4 acc chains. (c) wt x8 -> 1 kernel, zero x2 -> 1 (27 dispatches).
// ---------------------------------------------------------------------------

#define TPB 256

using bf16x8 = __attribute__((ext_vector_type(8))) __bf16;
using f32x4  = __attribute__((ext_vector_type(4))) float;

__device__ __forceinline__ unsigned bf16rne(float x) {
    unsigned u = __float_as_uint(x);
    return (u + 0x7fffu + ((u >> 16) & 1u)) >> 16;
}

// async global->LDS, 16B per lane. l is the WAVE-UNIFORM base; HW adds lane*16.
__device__ __forceinline__ void stage16(const unsigned short* g, unsigned short* l) {
#if __has_builtin(__builtin_amdgcn_global_load_lds)
    __builtin_amdgcn_global_load_lds((const __attribute__((address_space(1))) void*)g,
                                     (__attribute__((address_space(3))) void*)l, 16, 0, 0);
#else
    *(uint4*)((char*)l + (threadIdx.x & 63) * 16) = *(const uint4*)g;
#endif
}

// ---------------- graph prep kernels ----------------

__global__ void zero2_kernel(int* a, int* b, int n) {
    int i = blockIdx.x * blockDim.x + threadIdx.x;
    if (i < n) { a[i] = 0; b[i] = 0; }
}

__global__ void count_kernel(const int* __restrict__ dst, int* __restrict__ cnt, int E) {
    int e = blockIdx.x * blockDim.x + threadIdx.x;
    if (e < E) atomicAdd(&cnt[dst[e]], 1);
}

__global__ void dinv_kernel(const int* __restrict__ cnt, float* __restrict__ dinv, int n) {
    int i = blockIdx.x * blockDim.x + threadIdx.x;
    if (i < n) dinv[i] = rsqrtf((float)(cnt[i] + 1));
}

__global__ void scan1_kernel(const int* __restrict__ cnt, int* __restrict__ rowp,
                             int* __restrict__ bsums, int n) {
    __shared__ int sh[TPB];
    int t = threadIdx.x;
    int i = blockIdx.x * TPB + t;
    int v = (i < n) ? (cnt[i] + 1) : 0;       // +1 self loop in CSR
    sh[t] = v;
    __syncthreads();
    for (int off = 1; off < TPB; off <<= 1) {
        int x = (t >= off) ? sh[t - off] : 0;
        __syncthreads();
        sh[t] += x;
        __syncthreads();
    }
    if (i < n) rowp[i] = sh[t] - v;
    if (t == TPB - 1) bsums[blockIdx.x] = sh[t];
}

__global__ void scan2_kernel(int* __restrict__ bsums, int nb) {
    __shared__ int sh[TPB];
    int t = threadIdx.x;
    int v = (t < nb) ? bsums[t] : 0;
    sh[t] = v;
    __syncthreads();
    for (int off = 1; off < TPB; off <<= 1) {
        int x = (t >= off) ? sh[t - off] : 0;
        __syncthreads();
        sh[t] += x;
        __syncthreads();
    }
    if (t < nb) bsums[t] = sh[t] - v;
}

__global__ void scan3_kernel(int* __restrict__ rowp, const int* __restrict__ bsums, int n) {
    int i = blockIdx.x * TPB + threadIdx.x;
    if (i < n) rowp[i] += bsums[blockIdx.x];
}

// edge = u16 src | bf16(weight) << 16   (N=50000 < 65536)
__global__ void fill_kernel(const int* __restrict__ src, const int* __restrict__ dst,
                            const float* __restrict__ dinv,
                            const int* __restrict__ rowp, int* __restrict__ fill,
                            unsigned* __restrict__ edges, int E) {
    int e = blockIdx.x * blockDim.x + threadIdx.x;
    if (e >= E) return;
    int s = src[e], d = dst[e];
    int pos = rowp[d] + atomicAdd(&fill[d], 1);
    edges[pos] = (unsigned)s | (bf16rne(dinv[s] * dinv[d]) << 16);
}

__global__ void self_kernel(const int* __restrict__ cnt, const int* __restrict__ rowp,
                            const float* __restrict__ dinv, unsigned* __restrict__ edges,
                            int n) {
    int i = blockIdx.x * blockDim.x + threadIdx.x;
    if (i >= n) return;
    float dv = dinv[i];
    edges[rowp[i] + cnt[i]] = (unsigned)i | (bf16rne(dv * dv) << 16);
}

// ---------------- weight / input prep ----------------

struct WPtrs { const float* p[8]; };

// all 8 layer weights transposed+bf16'd in ONE dispatch.
// Wt[L][n*K + k] = bf16(W[L][k*N + n])
__global__ void wt_all_kernel(WPtrs wp, unsigned short* __restrict__ Wts) {
    const int cum[9] = {0, 16384, 40960, 90112, 155648, 221184, 286720, 335872, 360448};
    const int Ns[8] = {128, 192, 256, 256, 256, 256, 192, 128};
    const int Ks[8] = {128, 128, 192, 256, 256, 256, 256, 192};
    int id = blockIdx.x * blockDim.x + threadIdx.x;
    if (id >= 360448) return;
    int L = 0;
#pragma unroll
    for (int t = 1; t < 8; t++) if (id >= cum[t]) L = t;
    int lid = id - cum[L];
    int N = Ns[L], K = Ks[L];
    int k = lid / N, n = lid - k * N;
    Wts[cum[L] + n * K + k] = (unsigned short)bf16rne(wp.p[L][lid]);
}

__global__ void cvt_bf16_kernel(const float* __restrict__ in, unsigned short* __restrict__ out,
                                int n4) {
    int i = blockIdx.x * blockDim.x + threadIdx.x;
    if (i >= n4) return;
    float4 v = ((const float4*)in)[i];
    uint2 o;
    o.x = bf16rne(v.x) | (bf16rne(v.y) << 16);
    o.y = bf16rne(v.z) | (bf16rne(v.w) << 16);
    ((uint2*)out)[i] = o;
}

// ---------------- MFMA GEMM (operand-swapped) ----------------

// C[M,Nc] = A[M,K] @ W[K,Nc] (+bias,relu). A bf16 row-major, Wt bf16 [Nc][K].
// Operand swap: MFMA A-op = weight rows (feats), B-op = activation rows
// (nodes) -> D[row]=feat, D[col]=node; the 4 acc regs are 4 consecutive
// feats of one node -> packed b64 stores in both output layouts.
// 128 feats x 128 nodes per block, 4 waves, BK=64, K%64==0.
// XOR swizzle on the GLOBAL side of stage16 (LDS linear, conflict-free b128).
__global__ __launch_bounds__(256) void gemm_mfma_kernel(
    const unsigned short* __restrict__ A, const unsigned short* __restrict__ Wt,
    const float* __restrict__ bias, unsigned short* __restrict__ C,
    int M, int K, int Nc, int doBias, int doRelu, int outChunked) {
    __shared__ unsigned short Qb[128 * 64];   // activations (nodes x K-chunk)
    __shared__ unsigned short Pb[128 * 64];   // weights (feats x K-chunk)
    int tid = threadIdx.x;
    int l = tid & 63, w = tid >> 6;
    int node0 = blockIdx.x * 128, feat0 = blockIdx.y * 128;

    f32x4 acc[4][4];   // [i=feat tile][j=node tile]
#pragma unroll
    for (int i = 0; i < 4; i++)
#pragma unroll
        for (int j = 0; j < 4; j++) acc[i][j] = (f32x4){0.f, 0.f, 0.f, 0.f};

    const unsigned short* gQ[4];
    const unsigned short* gP[4];
    unsigned short* lQ[4];
    unsigned short* lP[4];
#pragma unroll
    for (int h = 0; h < 4; h++) {
        int slot = tid + h * 256;
        int r = slot >> 3, q = slot & 7;
        int qg = q ^ (r & 7);                  // global-side swizzle
        int nd = node0 + r; if (nd > M - 1) nd = M - 1;
        int ft = feat0 + r; if (ft > Nc - 1) ft = Nc - 1;
        gQ[h] = A + (size_t)nd * K + qg * 8;
        gP[h] = Wt + (size_t)ft * K + qg * 8;
        lQ[h] = Qb + (size_t)(w * 64 + h * 256) * 8;   // wave-uniform base
        lP[h] = Pb + (size_t)(w * 64 + h * 256) * 8;
    }

    int q4 = l >> 4, m16 = l & 15;
    int featHalf = w & 1, nodeHalf = w >> 1;
    int rP0 = featHalf * 64 + m16;
    int rQ0 = nodeHalf * 64 + m16;
    int sw = m16 & 7;

    for (int k0 = 0; k0 < K; k0 += 64) {
        __syncthreads();
#pragma unroll
        for (int h = 0; h < 4; h++) {
            stage16(gQ[h] + k0, lQ[h]);
            stage16(gP[h] + k0, lP[h]);
        }
        __syncthreads();
#pragma unroll
        for (int ko = 0; ko < 2; ko++) {
            bf16x8 pf[4], qf[4];
#pragma unroll
            for (int i = 0; i < 4; i++)
                pf[i] = *(const bf16x8*)(Pb + (rP0 + i * 16) * 64 + ((ko * 4 + q4) ^ sw) * 8);
#pragma unroll
            for (int j = 0; j < 4; j++)
                qf[j] = *(const bf16x8*)(Qb + (rQ0 + j * 16) * 64 + ((ko * 4 + q4) ^ sw) * 8);
#pragma unroll
            for (int i = 0; i < 4; i++)
#pragma unroll
                for (int j = 0; j < 4; j++)
                    acc[i][j] = __builtin_amdgcn_mfma_f32_16x16x32_bf16(pf[i], qf[j],
                                                                        acc[i][j], 0, 0, 0);
        }
    }

    // D layout: col(lane&15)=node, row(quad*4+reg)=feat -> 4 regs = 4 feats
#pragma unroll
    for (int i = 0; i < 4; i++) {
        int gf0 = feat0 + featHalf * 64 + i * 16 + q4 * 4;
        if (gf0 >= Nc) continue;               // gf0%4==0, Nc%64==0 -> gf0+3<Nc
        float4 bv = make_float4(0.f, 0.f, 0.f, 0.f);
        if (doBias) bv = *(const float4*)(bias + gf0);
        size_t cb = outChunked ? ((size_t)(gf0 >> 5) * ((size_t)M * 32) + (gf0 & 31))
                               : (size_t)gf0;
#pragma unroll
        for (int j = 0; j < 4; j++) {
            int gn = node0 + nodeHalf * 64 + j * 16 + m16;
            if (gn >= M) continue;
            f32x4 v = acc[i][j];
            float x0 = v[0] + bv.x, x1 = v[1] + bv.y;
            float x2 = v[2] + bv.z, x3 = v[3] + bv.w;
            if (doRelu) {
                x0 = fmaxf(x0, 0.f); x1 = fmaxf(x1, 0.f);
                x2 = fmaxf(x2, 0.f); x3 = fmaxf(x3, 0.f);
            }
            uint2 o;
            o.x = bf16rne(x0) | (bf16rne(x1) << 16);
            o.y = bf16rne(x2) | (bf16rne(x3) << 16);
            size_t off = outChunked ? (cb + (size_t)gn * 32) : (cb + (size_t)gn * Nc);
            *(uint2*)(C + off) = o;            // 8-B aligned: off%4==0 elems
        }
    }
}

// out[m] = dot(A[m,0:128], w[0:128])  A bf16 row-major, one wave per row
__global__ void gemv128_bf16_kernel(const unsigned short* __restrict__ A,
                                    const float* __restrict__ w,
                                    float* __restrict__ out, int M) {
    int wid = (blockIdx.x * blockDim.x + threadIdx.x) >> 6;
    int lane = threadIdx.x & 63;
    if (wid >= M) return;
    const unsigned short* a = A + (size_t)wid * 128;
    float a0 = __uint_as_float((unsigned)a[lane] << 16);
    float a1 = __uint_as_float((unsigned)a[lane + 64] << 16);
    float s = a0 * w[lane] + a1 * w[lane + 64];
#pragma unroll
    for (int off = 32; off > 0; off >>= 1) s += __shfl_down(s, off);
    if (lane == 0) out[wid] = s;
}

// ---------------- chunked aggregation, group-per-node ----------------

// Input: bf16 chunk-major [chunk][node][32f] (3.2 MB slice per chunk).
// Wave = 8 dst nodes x 8 lanes. Edge blocks of 8 are DOUBLE-BUFFERED (next
// block's coalesced load issues before current block's gathers), then all 8
// row gathers issue batched; 4 accumulator chains. Zero-padded edges: no
// inner guards. blockIdx%8 = XCD; chunk pinned per XCD (L2-resident slice).
__global__ __launch_bounds__(256) void agg_group_kernel(
    const uint2* __restrict__ in, const int* __restrict__ rowp,
    const int* __restrict__ cnt, const unsigned* __restrict__ edges,
    const float* __restrict__ bias, uint2* __restrict__ out,
    int nchunks, int NG /*node groups of 32*/, int n_nodes, int rowVec2,
    int doBias, int doRelu, int outChunked) {
    int xcd = blockIdx.x & 7;
    int slot = blockIdx.x >> 3;
    int chunk, shareIdx, shareCnt;
    if (nchunks == 8) { chunk = xcd; shareIdx = 0; shareCnt = 1; }
    else if (nchunks == 4) { chunk = xcd >> 1; shareIdx = xcd & 1; shareCnt = 2; }
    else {  // nchunks == 6: chunks 0,1 split across xcds {0,6} and {1,7}
        chunk = (xcd < 6) ? xcd : (xcd - 6);
        if (chunk < 2) { shareCnt = 2; shareIdx = (xcd < 6) ? 0 : 1; }
        else { shareCnt = 1; shareIdx = 0; }
    }
    int ngPerShare = (NG + shareCnt - 1) / shareCnt;
    if (slot >= ngPerShare) return;
    int ng = shareIdx * ngPerShare + slot;
    if (ng >= NG) return;

    int wave = threadIdx.x >> 6;
    int lane = threadIdx.x & 63;
    int group = lane >> 3, fl = lane & 7;
    int gb = lane & ~7;
    int node = ng * 32 + wave * 8 + group;
    if (node >= n_nodes) return;

    const uint2* slice = in + (size_t)chunk * n_nodes * 8;
    int s0 = rowp[node];
    int c = cnt[node] + 1;

    float ax[4] = {0.f, 0.f, 0.f, 0.f};
    float ay[4] = {0.f, 0.f, 0.f, 0.f};
    float az[4] = {0.f, 0.f, 0.f, 0.f};
    float aw[4] = {0.f, 0.f, 0.f, 0.f};

    unsigned ew = (fl < c) ? edges[s0 + fl] : 0u;        // block 0
    for (int base = 0; base < c; base += 8) {
        int nidx = base + 8 + fl;
        unsigned ewn = (nidx < c) ? edges[s0 + nidx] : 0u;   // prefetch next
        unsigned e[8];
#pragma unroll
        for (int j = 0; j < 8; j++) e[j] = (unsigned)__shfl((int)ew, gb + j);
        uint2 p[8];
#pragma unroll
        for (int j = 0; j < 8; j++) p[j] = slice[(int)(e[j] & 0xffffu) * 8 + fl];
#pragma unroll
        for (int j = 0; j < 8; j++) {
            float wgt = __uint_as_float(e[j] & 0xffff0000u);  // pad: +0.0
            int q = j & 3;
            ax[q] += wgt * __uint_as_float(p[j].x << 16);
            ay[q] += wgt * __uint_as_float(p[j].x & 0xffff0000u);
            az[q] += wgt * __uint_as_float(p[j].y << 16);
            aw[q] += wgt * __uint_as_float(p[j].y & 0xffff0000u);
        }
        ew = ewn;
    }
    float fx = (ax[0] + ax[1]) + (ax[2] + ax[3]);
    float fy = (ay[0] + ay[1]) + (ay[2] + ay[3]);
    float fz = (az[0] + az[1]) + (az[2] + az[3]);
    float fw = (aw[0] + aw[1]) + (aw[2] + aw[3]);

    if (doBias) {
        float4 bb = ((const float4*)bias)[chunk * 8 + fl];
        fx += bb.x; fy += bb.y; fz += bb.z; fw += bb.w;
    }
    if (doRelu) {
        fx = fmaxf(fx, 0.f); fy = fmaxf(fy, 0.f);
        fz = fmaxf(fz, 0.f); fw = fmaxf(fw, 0.f);
    }
    uint2 o;
    o.x = bf16rne(fx) | (bf16rne(fy) << 16);
    o.y = bf16rne(fz) | (bf16rne(fw) << 16);
    size_t oi = outChunked ? ((size_t)chunk * n_nodes * 8 + (size_t)node * 8 + fl)
                           : ((size_t)node * rowVec2 + chunk * 8 + fl);
    out[oi] = o;
}

// width-1 aggregation, fp32: one thread per node
__global__ void agg1_kernel(const float* __restrict__ in, const int* __restrict__ rowp,
                            const int* __restrict__ cnt, const unsigned* __restrict__ edges,
                            const float* __restrict__ bias, float* __restrict__ out,
                            int n_nodes, int doRelu) {
    int n = blockIdx.x * blockDim.x + threadIdx.x;
    if (n >= n_nodes) return;
    float acc = 0.f;
    int s0 = rowp[n];
    int c = cnt[n] + 1;
    for (int j = 0; j < c; j++) {
        unsigned e = edges[s0 + j];
        acc += __uint_as_float(e & 0xffff0000u) * in[e & 0xffffu];
    }
    acc += bias[0];
    if (doRelu) acc = fmaxf(acc, 0.f);
    out[n] = acc;
}

// ---------------- host launcher ----------------

extern "C" void kernel_launch(void* const* d_in, const int* in_sizes, int n_in,
                              void* d_out, int out_size, void* d_ws, size_t ws_size,
                              hipStream_t stream) {
    const float* x = (const float*)d_in[0];
    const int* ei = (const int*)d_in[1];
    const int Nn = in_sizes[0] / 128;      // 50000
    const int E = in_sizes[1] / 2;         // 800000
    const int* src = ei;
    const int* dst = ei + E;

    char* ws = (char*)d_ws;
    size_t off = 0;
    auto alloc = [&](size_t bytes) -> char* {
        char* p = ws + off;
        off = (off + bytes + 255) & ~(size_t)255;
        return p;
    };
    int* cnt = (int*)alloc((size_t)Nn * 4);
    int* fill = (int*)alloc((size_t)Nn * 4);
    int* rowp = (int*)alloc((size_t)Nn * 4);
    int* bsums = (int*)alloc(1024);
    float* dinv = (float*)alloc((size_t)Nn * 4);
    unsigned* edges = (unsigned*)alloc((size_t)(E + Nn) * 4);
    unsigned short* T = (unsigned short*)alloc((size_t)Nn * 256 * 2);
    unsigned short* H = (unsigned short*)alloc((size_t)Nn * 256 * 2);
    unsigned short* Bx = (unsigned short*)alloc((size_t)Nn * 128 * 2);
    float* F = (float*)alloc((size_t)Nn * 4);
    unsigned short* Wts = (unsigned short*)alloc((size_t)400000 * 2);
    (void)ws_size;

    const int dims[9][2] = {{128,128},{128,192},{192,256},{256,256},{256,256},
                            {256,256},{256,192},{192,128},{128,1}};
    unsigned short* Wt[8];
    {
        size_t o = 0;
        for (int i = 0; i < 8; i++) { Wt[i] = Wts + o; o += (size_t)dims[i][0] * dims[i][1]; }
    }

    int nbN = (Nn + TPB - 1) / TPB;
    int nbE = (E + TPB - 1) / TPB;

    // ---- graph prep ----
    zero2_kernel<<<nbN, TPB, 0, stream>>>(cnt, fill, Nn);
    count_kernel<<<nbE, TPB, 0, stream>>>(dst, cnt, E);
    dinv_kernel<<<nbN, TPB, 0, stream>>>(cnt, dinv, Nn);
    scan1_kernel<<<nbN, TPB, 0, stream>>>(cnt, rowp, bsums, Nn);
    scan2_kernel<<<1, TPB, 0, stream>>>(bsums, nbN);
    scan3_kernel<<<nbN, TPB, 0, stream>>>(rowp, bsums, Nn);
    fill_kernel<<<nbE, TPB, 0, stream>>>(src, dst, dinv, rowp, fill, edges, E);
    self_kernel<<<nbN, TPB, 0, stream>>>(cnt, rowp, dinv, edges, Nn);

    // ---- weight transpose (one dispatch) + input convert ----
    WPtrs wp;
    for (int i = 0; i < 8; i++) wp.p[i] = (const float*)d_in[2 + 2 * i];
    wt_all_kernel<<<(360448 + TPB - 1) / TPB, TPB, 0, stream>>>(wp, Wts);
    cvt_bf16_kernel<<<(Nn * 32 + TPB - 1) / TPB, TPB, 0, stream>>>(x, Bx, Nn * 32);

    auto gemm = [&](const unsigned short* A, int i, unsigned short* C, int K, int Nc,
                    int doBias, int doRelu, int outChunked) {
        const float* b = (const float*)d_in[3 + 2 * i];
        dim3 grid((Nn + 127) / 128, (Nc + 127) / 128);   // x: nodes, y: feats
        gemm_mfma_kernel<<<grid, 256, 0, stream>>>(A, Wt[i], b, C, Nn, K, Nc,
                                                   doBias, doRelu, outChunked);
    };
    int NG = (Nn + 31) / 32;
    auto agg = [&](const unsigned short* inb, unsigned short* outb, int w, int i,
                   int doBias, int doRelu, int outChunked) {
        int nch = w / 32;
        int blocksPerXcd = (nch == 4) ? (NG + 1) / 2 : NG;
        const float* b = (const float*)d_in[3 + 2 * i];
        agg_group_kernel<<<blocksPerXcd * 8, 256, 0, stream>>>(
            (const uint2*)inb, rowp, cnt, edges, b, (uint2*)outb,
            nch, NG, Nn, w / 4, doBias, doRelu, outChunked);
    };

    // layout chain: GEMM in=row, out=chunked (except G2: row); agg in=chunked,
    // out=row (except A0: chunked, feeds A1)
    gemm(Bx, 0, T, 128, 128, 0, 0, 1);      // G0: t = x@W0          -> T chunked
    agg(T, H, 128, 0, 1, 1, 1);             // A0: h1 = At+b0 relu   -> H chunked
    agg(H, T, 128, 1, 0, 0, 0);             // A1: u = A h1          -> T row
    gemm(T, 1, H, 128, 192, 1, 1, 1);       // G1: h2 = u@W1+b1 relu -> H chunked
    agg(H, T, 192, 2, 0, 0, 0);             // A2: u = A h2          -> T row
    gemm(T, 2, H, 192, 256, 1, 1, 0);       // G2: h3 = u@W2+b2 relu -> H row
    gemm(H, 3, T, 256, 256, 0, 0, 1);       // G3: t = h3@W3         -> T chunked
    agg(T, H, 256, 3, 1, 1, 0);             // A3: h4 = At+b3 relu   -> H row
    gemm(H, 4, T, 256, 256, 0, 0, 1);       // G4: t = h4@W4         -> T chunked
    agg(T, H, 256, 4, 1, 0, 0);             // A4: h5 = At+b4        -> H row
    gemm(H, 5, T, 256, 256, 0, 0, 1);       // G5: t = h5@W5         -> T chunked
    agg(T, H, 256, 5, 1, 1, 0);             // A5: h6 = At+b5 relu   -> H row
    gemm(H, 6, T, 256, 192, 0, 0, 1);       // G6: t = h6@W6         -> T chunked
    agg(T, H, 192, 6, 1, 1, 0);             // A6: h7 = At+b6 relu   -> H row
    gemm(H, 7, T, 192, 128, 0, 0, 1);       // G7: t = h7@W7         -> T chunked
    agg(T, H, 128, 7, 1, 1, 0);             // A7: h8 = At+b7 relu   -> H row
    gemv128_bf16_kernel<<<(Nn + 3) / 4, 256, 0, stream>>>(H, (const float*)d_in[2 + 16],
                                                          F, Nn);
    agg1_kernel<<<nbN, TPB, 0, stream>>>(F, rowp, cnt, edges, (const float*)d_in[3 + 16],
                                         (float*)d_out, Nn, 0);
}